// Round 7
// baseline (22284.834 us; speedup 1.0000x reference)
//
#include <hip/hip_runtime.h>
#include <hip/hip_fp16.h>
#include <math.h>

// Sizes: B=32, N=128, EMB=1024, HID=512, L=2, NCLS=7, IN_DIM=3072, TOK=4096
// Scan: column-ownership, capacity-tuned. 2 GNN pods x 64 WGs x 16 batches
// (WG owns 8 h-cols => 48 gate cols, 16 V cols; 130 KB weight slice;
// 16 WGs/XCD x 130 KB ~= 2.1 MB < 4 MiB L2). V history in fp16 (private per
// WG). LSTM on WGs 128..255: 2 pods x 64 WGs (pod = 64 rows, WG = 8 hid
// cols), exits after 32 steps. Cross-WG data via sc1 (stc/ldc) only.

#define AGENT __HIP_MEMORY_SCOPE_AGENT

__device__ __forceinline__ float ldc(const float* p) {
    return __hip_atomic_load(p, __ATOMIC_RELAXED, AGENT);
}
__device__ __forceinline__ void stc(float* p, float v) {
    __hip_atomic_store(p, v, __ATOMIC_RELAXED, AGENT);
}

__device__ __forceinline__ void podbar(int* bar, int nwg) {
    __syncthreads();
    if (threadIdx.x == 0) {
        int g = __hip_atomic_load(bar + 1, __ATOMIC_RELAXED, AGENT);
        int v = __hip_atomic_fetch_add(bar, 1, __ATOMIC_RELAXED, AGENT);
        if (v == nwg - 1) {
            __hip_atomic_store(bar, 0, __ATOMIC_RELAXED, AGENT);
            __builtin_amdgcn_s_waitcnt(0);
            __hip_atomic_store(bar + 1, g + 1, __ATOMIC_RELAXED, AGENT);
        } else {
            while (__hip_atomic_load(bar + 1, __ATOMIC_RELAXED, AGENT) == g) {
                __builtin_amdgcn_s_sleep(1);
            }
        }
        __asm__ __volatile__("" ::: "memory");
    }
    __syncthreads();
}

__global__ void init_bar(int* bar) { bar[threadIdx.x] = 0; }

__device__ __forceinline__ float sigf(float x) { return 1.f / (1.f + __expf(-x)); }

// ---------------------------------------------------------------------------
// Generic fp32 GEMM: C = act(A[M,K] @ W[N,K]^T + bias). 64x64 tile.
// ---------------------------------------------------------------------------
__global__ __launch_bounds__(256) void gemm_nt(
    const float* __restrict__ A, const float* __restrict__ W,
    const float* __restrict__ bias, float* __restrict__ C,
    int M, int N, int K, int relu)
{
    __shared__ float As[16][68];
    __shared__ float Ws[16][68];
    const int tid = threadIdx.x;
    const int m0 = blockIdx.x * 64;
    const int n0 = blockIdx.y * 64;
    const int lr = tid >> 2;
    const int lk = (tid & 3) << 2;
    const int tm = (tid & 15) << 2;
    const int tn = (tid >> 4) << 2;
    float acc[4][4] = {};
    const float* Aptr = A + (size_t)(m0 + lr) * K + lk;
    const float* Wptr = W + (size_t)(n0 + lr) * K + lk;
    for (int k0 = 0; k0 < K; k0 += 16) {
        __syncthreads();
        const float4 av = *(const float4*)(Aptr + k0);
        const float4 wv = *(const float4*)(Wptr + k0);
        As[lk + 0][lr] = av.x; As[lk + 1][lr] = av.y;
        As[lk + 2][lr] = av.z; As[lk + 3][lr] = av.w;
        Ws[lk + 0][lr] = wv.x; Ws[lk + 1][lr] = wv.y;
        Ws[lk + 2][lr] = wv.z; Ws[lk + 3][lr] = wv.w;
        __syncthreads();
        #pragma unroll
        for (int kk = 0; kk < 16; ++kk) {
            float a[4], b[4];
            #pragma unroll
            for (int u = 0; u < 4; ++u) { a[u] = As[kk][tm + u]; b[u] = Ws[kk][tn + u]; }
            #pragma unroll
            for (int ii = 0; ii < 4; ++ii)
                #pragma unroll
                for (int jj = 0; jj < 4; ++jj)
                    acc[ii][jj] += a[ii] * b[jj];
        }
    }
    #pragma unroll
    for (int ii = 0; ii < 4; ++ii)
        #pragma unroll
        for (int jj = 0; jj < 4; ++jj) {
            float v = acc[ii][jj] + bias[n0 + tn + jj];
            if (relu) v = fmaxf(v, 0.f);
            C[(size_t)(m0 + tm + ii) * N + n0 + tn + jj] = v;
        }
}

// ---------------------------------------------------------------------------
// mlp0 with fused 5-way concat
// ---------------------------------------------------------------------------
__global__ __launch_bounds__(256) void gemm_cat(
    const float* __restrict__ H0, const float* __restrict__ H1,
    const float* __restrict__ H2, const float* __restrict__ feat,
    const float* __restrict__ lstm, const float* __restrict__ W,
    const float* __restrict__ bias, float* __restrict__ C)
{
    __shared__ float As[16][68];
    __shared__ float Ws[16][68];
    const int tid = threadIdx.x;
    const int m0 = blockIdx.x * 64;
    const int n0 = blockIdx.y * 64;
    const int lr = tid >> 2;
    const int lk = (tid & 3) << 2;
    const int tm = (tid & 15) << 2;
    const int tn = (tid >> 4) << 2;
    float acc[4][4] = {};
    for (int k0 = 0; k0 < 3072; k0 += 16) {
        const float* src; int kloc, Kp;
        if (k0 < 512)       { src = H0;   kloc = k0;        Kp = 512;  }
        else if (k0 < 1024) { src = H1;   kloc = k0 - 512;  Kp = 512;  }
        else if (k0 < 1536) { src = H2;   kloc = k0 - 1024; Kp = 512;  }
        else if (k0 < 2560) { src = feat; kloc = k0 - 1536; Kp = 1024; }
        else                { src = lstm; kloc = k0 - 2560; Kp = 512;  }
        __syncthreads();
        const float4 av = *(const float4*)(src + (size_t)(m0 + lr) * Kp + kloc + lk);
        const float4 wv = *(const float4*)(W + (size_t)(n0 + lr) * 3072 + k0 + lk);
        As[lk + 0][lr] = av.x; As[lk + 1][lr] = av.y;
        As[lk + 2][lr] = av.z; As[lk + 3][lr] = av.w;
        Ws[lk + 0][lr] = wv.x; Ws[lk + 1][lr] = wv.y;
        Ws[lk + 2][lr] = wv.z; Ws[lk + 3][lr] = wv.w;
        __syncthreads();
        #pragma unroll
        for (int kk = 0; kk < 16; ++kk) {
            float a[4], b[4];
            #pragma unroll
            for (int u = 0; u < 4; ++u) { a[u] = As[kk][tm + u]; b[u] = Ws[kk][tn + u]; }
            #pragma unroll
            for (int ii = 0; ii < 4; ++ii)
                #pragma unroll
                for (int jj = 0; jj < 4; ++jj)
                    acc[ii][jj] += a[ii] * b[jj];
        }
    }
    #pragma unroll
    for (int ii = 0; ii < 4; ++ii)
        #pragma unroll
        for (int jj = 0; jj < 4; ++jj) {
            float v = fmaxf(acc[ii][jj] + bias[n0 + tn + jj], 0.f);
            C[(size_t)(m0 + tm + ii) * 512 + n0 + tn + jj] = v;
        }
}

// ---------------------------------------------------------------------------
// One GNN layer scan. Grid 256.
//   WG 0..127  : 2 GNN pods x 64 WGs, 16 batches/pod. WG w owns h-cols
//                [8w,8w+8): 48 gate cols, 16 V cols, 8 M' cols.
//   WG 128..255: LSTM (scan0 only): 2 pods x 64 WGs; pod = rows [64p,64p+64),
//                WG = 8 hid cols; h staged in 4x16-row LDS chunks; exits @32.
// ---------------------------------------------------------------------------
__global__ __launch_bounds__(256, 1) void scan_layer(
    const float* __restrict__ Hin, float* __restrict__ Hout,
    const float* __restrict__ adj, const float* __restrict__ smk,
    const float* __restrict__ preQc, const float* __restrict__ preQp,
    const float* __restrict__ cWhh, const float* __restrict__ pWih,
    const float* __restrict__ cbhh, const float* __restrict__ pbih,
    const float* __restrict__ attnW,
    const float* __restrict__ Wr0, const float* __restrict__ Wr1,
    float* __restrict__ Mbuf, float* __restrict__ hxch, __half* __restrict__ Vh,
    int* __restrict__ bar, const int with_lstm,
    const float* __restrict__ gi, const float* __restrict__ lstm_Whh,
    const float* __restrict__ lstm_bhh, float* __restrict__ lstm_hbuf,
    float* __restrict__ lstm_out)
{
    __shared__ float Ms[16 * 520];   // stage: M/h (GNN) or 16-row h chunk (LSTM)
    __shared__ float eh[16 * 128];   // hk history per batch
    __shared__ float wsf[16 * 128];  // softmax numerators
    __shared__ float gg[16 * 48];    // GNN gate slice | LSTM gate combine (512)
    __shared__ float wkL[512];
    __shared__ float invZ[16];

    const int wg = blockIdx.x, tid = threadIdx.x;

    if (wg >= 128) {
        // =========================== LSTM ================================
        if (!with_lstm) return;
        const int lw = wg - 128;
        const int lp = lw >> 6;          // 0..1 : rows [64*lp, 64*lp+64)
        const int wc = lw & 63;          // owns hid cols [8*wc, 8*wc+8)
        int* pbar = bar + (2 + lp) * 64;
        const int row0 = lp * 64;
        const int u = tid & 15, rr = tid >> 4;       // rr = row in chunk
        const int jc = u & 7, gp = u >> 3;           // gates {2gp, 2gp+1}
        const int ghid = wc * 8 + jc;
        const float* wA = lstm_Whh + (size_t)((2 * gp) * 512 + ghid) * 512;
        const float* wB = lstm_Whh + (size_t)((2 * gp + 1) * 512 + ghid) * 512;
        const float bA = lstm_bhh[(2 * gp) * 512 + ghid];
        const float bB = lstm_bhh[(2 * gp + 1) * 512 + ghid];
        float c4[4] = {0.f, 0.f, 0.f, 0.f};
        for (int t = 0; t < 32; ++t) {
            const int par = t & 1;
            for (int rc = 0; rc < 4; ++rc) {
                if (t > 0) {
                    const float* hsrc = lstm_hbuf + (size_t)par * 65536
                                      + (size_t)(row0 + rc * 16) * 512;
                    for (int s = tid; s < 8192; s += 256)
                        Ms[(s >> 9) * 520 + (s & 511)] =
                            ldc(hsrc + (size_t)(s >> 9) * 512 + (s & 511));
                }
                __syncthreads();
                const int grow = row0 + rc * 16 + rr;
                const float* gir = gi + ((size_t)t * 128 + grow) * 2048;
                float sA = bA + gir[(2 * gp) * 512 + ghid];
                float sB = bB + gir[(2 * gp + 1) * 512 + ghid];
                if (t > 0) {
                    const float* hr = Ms + rr * 520;
                    for (int k = 0; k < 512; k += 4) {
                        const float4 h4 = *(const float4*)(hr + k);
                        const float4 a4 = *(const float4*)(wA + k);
                        const float4 b4 = *(const float4*)(wB + k);
                        sA += h4.x*a4.x + h4.y*a4.y + h4.z*a4.z + h4.w*a4.w;
                        sB += h4.x*b4.x + h4.y*b4.y + h4.z*b4.z + h4.w*b4.w;
                    }
                }
                gg[rr * 32 + jc * 4 + 2 * gp]     = sA;
                gg[rr * 32 + jc * 4 + 2 * gp + 1] = sB;
                __syncthreads();
                if (tid < 128) {
                    const int r2 = tid >> 3, j2 = tid & 7;
                    const int grw = row0 + rc * 16 + r2;
                    const int gh2 = wc * 8 + j2;
                    const float si = gg[r2 * 32 + j2 * 4 + 0];
                    const float sf = gg[r2 * 32 + j2 * 4 + 1];
                    const float sg = gg[r2 * 32 + j2 * 4 + 2];
                    const float so = gg[r2 * 32 + j2 * 4 + 3];
                    const float c = sigf(sf) * c4[rc] + sigf(si) * tanhf(sg);
                    c4[rc] = c;
                    const float h = sigf(so) * tanhf(c);
                    stc(lstm_hbuf + (size_t)(1 - par) * 65536 + (size_t)grw * 512 + gh2, h);
                    lstm_out[((size_t)t * 128 + grw) * 512 + gh2] = h;
                }
                __syncthreads();
            }
            podbar(pbar, 64);
        }
        return;
    }

    // ============================= GNN ==================================
    const int pod = wg >> 6, w = wg & 63;
    int* pbar = bar + pod * 64;
    const int b0 = pod * 16;
    const int J0 = w * 8;
    const int bq = tid >> 4, u = tid & 15;
    const int jc = u & 7, gp = u >> 3;

    for (int s = tid; s < 512; s += 256) wkL[s] = attnW[512 + s];

    // precompute the 3 gate-weight rows / biases this thread owns
    const float* wr_[3]; float bi_[3];
    #pragma unroll
    for (int r = 0; r < 3; ++r) {
        const int g = gp + 2 * r;
        if (g < 3) { wr_[r] = cWhh + (size_t)(g * 512 + J0 + jc) * 512;
                     bi_[r] = cbhh[g * 512 + J0 + jc]; }
        else       { wr_[r] = pWih + (size_t)((g - 3) * 512 + J0 + jc) * 512;
                     bi_[r] = pbih[(g - 3) * 512 + J0 + jc]; }
    }
    // V-projection row (16 cols per WG: 8 of Wr0, 8 of Wr1)
    const float* vrow = (u < 8) ? Wr0 + (size_t)(J0 + u) * 512
                                : Wr1 + (size_t)(J0 + u - 8) * 512;

    // zero this pod's M
    for (int s = w * 256 + tid; s < 8192; s += 16384) stc(Mbuf + pod * 8192 + s, 0.f);
    podbar(pbar, 64);

    for (int i = 0; i < 128; ++i) {
        // ----------------- Phase 1: GG + gates -> h ----------------------
        for (int s = tid; s < 8192; s += 256)
            Ms[(s >> 9) * 520 + (s & 511)] = ldc(Mbuf + pod * 8192 + s);
        __syncthreads();
        {
            const float* mrow = Ms + bq * 520;
            float a0 = 0.f, a1 = 0.f, a2 = 0.f;
            for (int k = 0; k < 512; k += 4) {
                const float4 m4 = *(const float4*)(mrow + k);
                const float4 w0 = *(const float4*)(wr_[0] + k);
                const float4 w1 = *(const float4*)(wr_[1] + k);
                const float4 w2 = *(const float4*)(wr_[2] + k);
                a0 += m4.x*w0.x + m4.y*w0.y + m4.z*w0.z + m4.w*w0.w;
                a1 += m4.x*w1.x + m4.y*w1.y + m4.z*w1.z + m4.w*w1.w;
                a2 += m4.x*w2.x + m4.y*w2.y + m4.z*w2.z + m4.w*w2.w;
            }
            gg[bq * 48 + (gp + 0) * 8 + jc] = a0 + bi_[0];
            gg[bq * 48 + (gp + 2) * 8 + jc] = a1 + bi_[1];
            gg[bq * 48 + (gp + 4) * 8 + jc] = a2 + bi_[2];
        }
        __syncthreads();
        if (tid < 128) {
            const int bb = tid >> 3, hc = tid & 7, j = J0 + hc;
            const int bgl = b0 + bb;
            const float g0v = gg[bb * 48 + hc];
            const float g1v = gg[bb * 48 + 8 + hc];
            const float g2v = gg[bb * 48 + 16 + hc];
            const float g3v = gg[bb * 48 + 24 + hc];
            const float g4v = gg[bb * 48 + 32 + hc];
            const float g5v = gg[bb * 48 + 40 + hc];
            const float mv  = Ms[bb * 520 + j];
            const float* pc = preQc + ((size_t)bgl * 128 + i) * 1536;
            const float* pp = preQp + ((size_t)bgl * 128 + i) * 1536;
            const float qv  = Hin[((size_t)bgl * 128 + i) * 512 + j];
            const float rc = sigf(pc[j] + g0v);
            const float zc = sigf(pc[512 + j] + g1v);
            const float nc = tanhf(pc[1024 + j] + rc * g2v);
            const float oc = (1.f - zc) * nc + zc * mv;
            const float rp = sigf(g3v + pp[j]);
            const float zp = sigf(g4v + pp[512 + j]);
            const float np = tanhf(g5v + rp * pp[1024 + j]);
            const float op = (1.f - zp) * np + zp * qv;
            const float h = oc + op;
            stc(hxch + pod * 8192 + bb * 512 + j, h);
            Hout[((size_t)bgl * 128 + i) * 512 + j] = h;
        }
        podbar(pbar, 64);

        // ----------------- Phase 2: hk, V, softmax, M' -------------------
        for (int s = tid; s < 8192; s += 256)
            Ms[(s >> 9) * 520 + (s & 511)] = ldc(hxch + pod * 8192 + s);
        __syncthreads();
        {   // hk: lane-contiguous partials + in-wave reduce (width 16)
            const float* hr = Ms + bq * 520;
            float p = 0.f;
            #pragma unroll
            for (int kk = 0; kk < 32; ++kk) {
                const int k = u + kk * 16;
                p += hr[k] * wkL[k];
            }
            #pragma unroll
            for (int off = 8; off > 0; off >>= 1) p += __shfl_xor(p, off, 16);
            if (u == 0) eh[bq * 128 + i] = p;
        }
        // V projection: 16 cols per WG, fp16 private history
        {
            const float* hr = Ms + bq * 520;
            float v = 0.f;
            for (int k = 0; k < 512; k += 4) {
                const float4 h4 = *(const float4*)(hr + k);
                const float4 w4 = *(const float4*)(vrow + k);
                v += h4.x*w4.x + h4.y*w4.y + h4.z*w4.z + h4.w*w4.w;
            }
            Vh[(((size_t)wg * 16 + bq) * 128 + i) * 16 + u] = __float2half(v);
        }
        __syncthreads();   // eh[i] visible to all lanes of group bq
        if (i < 127) {
            const float* arow = adj + ((size_t)(b0 + bq) * 128 + (i + 1)) * 128;
            float amx = -3.0e38f;
            for (int n = u; n <= i; n += 16)
                amx = fmaxf(amx, eh[bq * 128 + n] - (1.f - arow[n]) * 1e30f);
            #pragma unroll
            for (int off = 8; off > 0; off >>= 1)
                amx = fmaxf(amx, __shfl_xor(amx, off, 16));
            float es = 0.f;
            for (int n = u; n <= i; n += 16) {
                const float e = __expf(eh[bq * 128 + n] - (1.f - arow[n]) * 1e30f - amx);
                wsf[bq * 128 + n] = e;
                es += e;
            }
            #pragma unroll
            for (int off = 8; off > 0; off >>= 1) es += __shfl_xor(es, off, 16);
            if (u == 0) invZ[bq] = 1.f / es;
            __syncthreads();
            if (tid < 128) {
                const int bb = tid >> 3, hc = tid & 7;
                const float* srow = smk + ((size_t)(b0 + bb) * 128 + (i + 1)) * 128;
                const __half* vb = Vh + (((size_t)wg * 16 + bb) * 128) * 16;
                float acc = 0.f;
                for (int n = 0; n <= i; ++n) {
                    const float wgt = wsf[bb * 128 + n];
                    const __half v0 = vb[n * 16 + hc];
                    const __half v1 = vb[n * 16 + 8 + hc];
                    acc += wgt * __half2float((srow[n] != 0.f) ? v0 : v1);
                }
                stc(Mbuf + pod * 8192 + bb * 512 + J0 + hc, acc * invZ[bb]);
            }
        }
        podbar(pbar, 64);
    }
}

// ---------------------------------------------------------------------------
__global__ __launch_bounds__(256) void out_gemm(
    const float* __restrict__ x2, const float* __restrict__ W,
    const float* __restrict__ bias, float* __restrict__ out)
{
    __shared__ float xs[16 * 516];
    const int tid = threadIdx.x;
    const int r0 = blockIdx.x * 16;
    for (int idx = tid; idx < 16 * 512; idx += 256) {
        const int rr = idx >> 9, kk = idx & 511;
        xs[rr * 516 + kk] = x2[(size_t)(r0 + rr) * 512 + kk];
    }
    __syncthreads();
    if (tid < 128) {
        const int r = tid >> 3, c = tid & 7;
        if (c < 7) {
            float acc = bias[c];
            const float* wr = W + c * 512;
            const float* xr = xs + r * 516;
            for (int k = 0; k < 512; ++k) acc += xr[k] * wr[k];
            out[(size_t)(r0 + r) * 7 + c] = acc;
        }
    }
}

// ---------------------------------------------------------------------------
extern "C" void kernel_launch(void* const* d_in, const int* in_sizes, int n_in,
                              void* d_out, int out_size, void* d_ws, size_t ws_size,
                              hipStream_t stream) {
    (void)in_sizes; (void)n_in; (void)out_size; (void)ws_size;
    const float* feat     = (const float*)d_in[0];
    const float* adj      = (const float*)d_in[1];
    const float* smask    = (const float*)d_in[2];
    const float* lstm_Wih = (const float*)d_in[5];
    const float* lstm_Whh = (const float*)d_in[6];
    const float* lstm_bih = (const float*)d_in[7];
    const float* lstm_bhh = (const float*)d_in[8];
    const float* fc1_W    = (const float*)d_in[9];
    const float* fc1_b    = (const float*)d_in[10];
    const float* attn_W   = (const float*)d_in[11];
    const float* Wr0      = (const float*)d_in[13];
    const float* Wr1      = (const float*)d_in[14];
    const float* gruC_Wih = (const float*)d_in[15];
    const float* gruC_Whh = (const float*)d_in[16];
    const float* gruC_bih = (const float*)d_in[17];
    const float* gruC_bhh = (const float*)d_in[18];
    const float* gruP_Wih = (const float*)d_in[19];
    const float* gruP_Whh = (const float*)d_in[20];
    const float* gruP_bih = (const float*)d_in[21];
    const float* gruP_bhh = (const float*)d_in[22];
    const float* mlp0_W   = (const float*)d_in[23];
    const float* mlp0_b   = (const float*)d_in[24];
    const float* mlp1_W   = (const float*)d_in[25];
    const float* mlp1_b   = (const float*)d_in[26];
    const float* out_W    = (const float*)d_in[27];
    const float* out_b    = (const float*)d_in[28];

    float* ws       = (float*)d_ws;
    float* lstm_gi  = ws;                       // 8,388,608
    float* lstm_out = lstm_gi + 8388608;        // 2,097,152
    float* H0       = lstm_out + 2097152;       // 2,097,152
    float* H1       = H0 + 2097152;             // 2,097,152
    float* H2       = H1 + 2097152;             // 2,097,152
    float* preQc    = H2 + 2097152;             // 6,291,456
    float* preQp    = preQc + 6291456;          // 6,291,456
    float* x1       = preQp + 6291456;          // 2,097,152
    float* x2       = x1 + 2097152;             // 2,097,152
    float* Mbuf     = x2 + 2097152;             // 16,384 [pod][16][512]
    float* hxch     = Mbuf + 16384;             // 16,384 [pod][16][512]
    __half* Vh      = (__half*)(hxch + 16384);  // 4,194,304 halfs (2,097,152 f)
    float* lstm_hb  = hxch + 16384 + 2097152;   // 131,072 [2][128][512]
    int*   bar      = (int*)(lstm_hb + 131072); // 1,024 ints

    const dim3 blk(256);
    init_bar<<<1, 1024, 0, stream>>>(bar);

    // parallel-phase GEMMs
    gemm_nt<<<dim3(64, 8), blk, 0, stream>>>(feat, fc1_W, fc1_b, H0, 4096, 512, 1024, 1);
    gemm_nt<<<dim3(64, 32), blk, 0, stream>>>(feat, lstm_Wih, lstm_bih, lstm_gi, 4096, 2048, 1024, 0);
    gemm_nt<<<dim3(64, 24), blk, 0, stream>>>(H0, gruC_Wih, gruC_bih, preQc, 4096, 1536, 512, 0);
    gemm_nt<<<dim3(64, 24), blk, 0, stream>>>(H0, gruP_Whh, gruP_bhh, preQp, 4096, 1536, 512, 0);

    // layer 0 scan (+ LSTM on WGs 128..255)
    scan_layer<<<256, blk, 0, stream>>>(
        H0, H1, adj, smask, preQc, preQp,
        gruC_Whh, gruP_Wih, gruC_bhh, gruP_bih, attn_W,
        Wr0, Wr1, Mbuf, hxch, Vh, bar, 1,
        lstm_gi, lstm_Whh, lstm_bhh, lstm_hb, lstm_out);

    // layer-1 preQ
    gemm_nt<<<dim3(64, 24), blk, 0, stream>>>(H1, gruC_Wih + (size_t)1536 * 512,
                                              gruC_bih + 1536, preQc, 4096, 1536, 512, 0);
    gemm_nt<<<dim3(64, 24), blk, 0, stream>>>(H1, gruP_Whh + (size_t)1536 * 512,
                                              gruP_bhh + 1536, preQp, 4096, 1536, 512, 0);

    // layer 1 scan
    scan_layer<<<256, blk, 0, stream>>>(
        H1, H2, adj, smask, preQc, preQp,
        gruC_Whh + (size_t)1536 * 512, gruP_Wih + (size_t)1536 * 512,
        gruC_bhh + 1536, gruP_bih + 1536, attn_W + 1024,
        Wr0 + (size_t)512 * 512, Wr1 + (size_t)512 * 512,
        Mbuf, hxch, Vh, bar, 0,
        lstm_gi, lstm_Whh, lstm_bhh, lstm_hb, lstm_out);

    // head
    gemm_cat<<<dim3(64, 8), blk, 0, stream>>>(H0, H1, H2, feat, lstm_out, mlp0_W, mlp0_b, x1);
    gemm_nt<<<dim3(64, 8), blk, 0, stream>>>(x1, mlp1_W, mlp1_b, x2, 4096, 512, 512, 1);
    out_gemm<<<256, blk, 0, stream>>>(x2, out_W, out_b, (float*)d_out);
}

// Round 8
// 8499.250 us; speedup vs baseline: 2.6220x; 2.6220x over previous
//
#include <hip/hip_runtime.h>
#include <math.h>

// Sizes: B=32, N=128, EMB=1024, HID=512, L=2, NCLS=7, IN_DIM=3072, TOK=4096
// Scan: weight-stationary MFMA. 2 GNN pods x 64 WGs x 16 batches. Each WG
// owns 8 h-cols; waves 0-2 hold gate-weight tiles (6 gates x 8 cols) and
// wave 3 holds the V tile ({Wr0|Wr1} 8+8 cols) as bf16 hi/lo B-fragments in
// VGPRs (loaded once). Per step: stage M (bf16) -> 32 MFMAs -> gates/h local
// -> exchange h -> stage h -> V MFMA + hk + softmax + M'. 2 pod barriers.
// Zero weight traffic in the scan. LSTM on WGs 128..255 (layer-0 launch).

typedef __attribute__((ext_vector_type(4))) float f32x4;
typedef __attribute__((ext_vector_type(8))) short s16x8;

#define AGENT __HIP_MEMORY_SCOPE_AGENT

__device__ __forceinline__ float ldc(const float* p) {
    return __hip_atomic_load(p, __ATOMIC_RELAXED, AGENT);
}
__device__ __forceinline__ void stc(float* p, float v) {
    __hip_atomic_store(p, v, __ATOMIC_RELAXED, AGENT);
}
__device__ __forceinline__ unsigned ldcu(const unsigned* p) {
    return __hip_atomic_load(p, __ATOMIC_RELAXED, AGENT);
}
__device__ __forceinline__ void stcu(unsigned* p, unsigned v) {
    __hip_atomic_store(p, v, __ATOMIC_RELAXED, AGENT);
}

__device__ __forceinline__ void podbar(int* bar, int nwg) {
    __syncthreads();
    if (threadIdx.x == 0) {
        int g = __hip_atomic_load(bar + 1, __ATOMIC_RELAXED, AGENT);
        int v = __hip_atomic_fetch_add(bar, 1, __ATOMIC_RELAXED, AGENT);
        if (v == nwg - 1) {
            __hip_atomic_store(bar, 0, __ATOMIC_RELAXED, AGENT);
            __builtin_amdgcn_s_waitcnt(0);
            __hip_atomic_store(bar + 1, g + 1, __ATOMIC_RELAXED, AGENT);
        } else {
            while (__hip_atomic_load(bar + 1, __ATOMIC_RELAXED, AGENT) == g) {
                __builtin_amdgcn_s_sleep(1);
            }
        }
        __asm__ __volatile__("" ::: "memory");
    }
    __syncthreads();
}

__global__ void init_bar(int* bar) { bar[threadIdx.x] = 0; }

__device__ __forceinline__ float sigf(float x) { return 1.f / (1.f + __expf(-x)); }

// fp32 -> bf16 (RNE) and back
__device__ __forceinline__ unsigned short f2bf(float f) {
    unsigned u = __float_as_uint(f);
    return (unsigned short)((u + 0x7fffu + ((u >> 16) & 1u)) >> 16);
}
__device__ __forceinline__ float bf2f(unsigned short h) {
    return __uint_as_float(((unsigned)h) << 16);
}

// ---------------------------------------------------------------------------
// Generic fp32 GEMM: C = act(A[M,K] @ W[N,K]^T + bias). 64x64 tile.
// ---------------------------------------------------------------------------
__global__ __launch_bounds__(256) void gemm_nt(
    const float* __restrict__ A, const float* __restrict__ W,
    const float* __restrict__ bias, float* __restrict__ C,
    int M, int N, int K, int relu)
{
    __shared__ float As[16][68];
    __shared__ float Ws[16][68];
    const int tid = threadIdx.x;
    const int m0 = blockIdx.x * 64;
    const int n0 = blockIdx.y * 64;
    const int lr = tid >> 2;
    const int lk = (tid & 3) << 2;
    const int tm = (tid & 15) << 2;
    const int tn = (tid >> 4) << 2;
    float acc[4][4] = {};
    const float* Aptr = A + (size_t)(m0 + lr) * K + lk;
    const float* Wptr = W + (size_t)(n0 + lr) * K + lk;
    for (int k0 = 0; k0 < K; k0 += 16) {
        __syncthreads();
        const float4 av = *(const float4*)(Aptr + k0);
        const float4 wv = *(const float4*)(Wptr + k0);
        As[lk + 0][lr] = av.x; As[lk + 1][lr] = av.y;
        As[lk + 2][lr] = av.z; As[lk + 3][lr] = av.w;
        Ws[lk + 0][lr] = wv.x; Ws[lk + 1][lr] = wv.y;
        Ws[lk + 2][lr] = wv.z; Ws[lk + 3][lr] = wv.w;
        __syncthreads();
        #pragma unroll
        for (int kk = 0; kk < 16; ++kk) {
            float a[4], b[4];
            #pragma unroll
            for (int u = 0; u < 4; ++u) { a[u] = As[kk][tm + u]; b[u] = Ws[kk][tn + u]; }
            #pragma unroll
            for (int ii = 0; ii < 4; ++ii)
                #pragma unroll
                for (int jj = 0; jj < 4; ++jj)
                    acc[ii][jj] += a[ii] * b[jj];
        }
    }
    #pragma unroll
    for (int ii = 0; ii < 4; ++ii)
        #pragma unroll
        for (int jj = 0; jj < 4; ++jj) {
            float v = acc[ii][jj] + bias[n0 + tn + jj];
            if (relu) v = fmaxf(v, 0.f);
            C[(size_t)(m0 + tm + ii) * N + n0 + tn + jj] = v;
        }
}

// ---------------------------------------------------------------------------
// mlp0 with fused 5-way concat
// ---------------------------------------------------------------------------
__global__ __launch_bounds__(256) void gemm_cat(
    const float* __restrict__ H0, const float* __restrict__ H1,
    const float* __restrict__ H2, const float* __restrict__ feat,
    const float* __restrict__ lstm, const float* __restrict__ W,
    const float* __restrict__ bias, float* __restrict__ C)
{
    __shared__ float As[16][68];
    __shared__ float Ws[16][68];
    const int tid = threadIdx.x;
    const int m0 = blockIdx.x * 64;
    const int n0 = blockIdx.y * 64;
    const int lr = tid >> 2;
    const int lk = (tid & 3) << 2;
    const int tm = (tid & 15) << 2;
    const int tn = (tid >> 4) << 2;
    float acc[4][4] = {};
    for (int k0 = 0; k0 < 3072; k0 += 16) {
        const float* src; int kloc, Kp;
        if (k0 < 512)       { src = H0;   kloc = k0;        Kp = 512;  }
        else if (k0 < 1024) { src = H1;   kloc = k0 - 512;  Kp = 512;  }
        else if (k0 < 1536) { src = H2;   kloc = k0 - 1024; Kp = 512;  }
        else if (k0 < 2560) { src = feat; kloc = k0 - 1536; Kp = 1024; }
        else                { src = lstm; kloc = k0 - 2560; Kp = 512;  }
        __syncthreads();
        const float4 av = *(const float4*)(src + (size_t)(m0 + lr) * Kp + kloc + lk);
        const float4 wv = *(const float4*)(W + (size_t)(n0 + lr) * 3072 + k0 + lk);
        As[lk + 0][lr] = av.x; As[lk + 1][lr] = av.y;
        As[lk + 2][lr] = av.z; As[lk + 3][lr] = av.w;
        Ws[lk + 0][lr] = wv.x; Ws[lk + 1][lr] = wv.y;
        Ws[lk + 2][lr] = wv.z; Ws[lk + 3][lr] = wv.w;
        __syncthreads();
        #pragma unroll
        for (int kk = 0; kk < 16; ++kk) {
            float a[4], b[4];
            #pragma unroll
            for (int u = 0; u < 4; ++u) { a[u] = As[kk][tm + u]; b[u] = Ws[kk][tn + u]; }
            #pragma unroll
            for (int ii = 0; ii < 4; ++ii)
                #pragma unroll
                for (int jj = 0; jj < 4; ++jj)
                    acc[ii][jj] += a[ii] * b[jj];
        }
    }
    #pragma unroll
    for (int ii = 0; ii < 4; ++ii)
        #pragma unroll
        for (int jj = 0; jj < 4; ++jj) {
            float v = fmaxf(acc[ii][jj] + bias[n0 + tn + jj], 0.f);
            C[(size_t)(m0 + tm + ii) * 512 + n0 + tn + jj] = v;
        }
}

// ---------------------------------------------------------------------------
// One GNN layer scan (weight-stationary MFMA). Grid 256 (layer 0) / 128.
// ---------------------------------------------------------------------------
__global__ __launch_bounds__(256, 1) void scan_layer(
    const float* __restrict__ Hin, float* __restrict__ Hout,
    const float* __restrict__ adj, const float* __restrict__ smk,
    const float* __restrict__ preQc, const float* __restrict__ preQp,
    const float* __restrict__ cWhh, const float* __restrict__ pWih,
    const float* __restrict__ cbhh, const float* __restrict__ pbih,
    const float* __restrict__ attnW,
    const float* __restrict__ Wr0, const float* __restrict__ Wr1,
    unsigned* __restrict__ Mbuf, unsigned* __restrict__ hxch,
    float* __restrict__ Vh, int* __restrict__ bar, const int with_lstm,
    const float* __restrict__ gi, const float* __restrict__ lstm_Whh,
    const float* __restrict__ lstm_bhh, float* __restrict__ lstm_hbuf,
    float* __restrict__ lstm_out)
{
    __shared__ __align__(16) unsigned char smemc[40448];
    unsigned short* MbU = (unsigned short*)smemc;        // 16x520 bf16
    float* wkL  = (float*)(smemc + 16640);               // 512
    float* eh   = (float*)(smemc + 18688);               // 16x128
    float* wsf  = (float*)(smemc + 26880);               // 16x128
    float* gg   = (float*)(smemc + 35072);               // 16x48
    float* vcur = (float*)(smemc + 38144);               // 16x16
    float* mpr  = (float*)(smemc + 39168);               // 16x8
    float* htmp = (float*)(smemc + 39680);               // 16x8
    float* invZ = (float*)(smemc + 40192);               // 16

    const int wg = blockIdx.x, tid = threadIdx.x;

    if (wg >= 128) {
        // =========================== LSTM (as R7) ========================
        if (!with_lstm) return;
        float* Msf = (float*)smemc;                      // 16x520 fp32
        float* lgg = (float*)(smemc + 33280);            // 512 fp32
        const int lw = wg - 128;
        const int lp = lw >> 6;
        const int wc = lw & 63;
        int* pbar = bar + (2 + lp) * 64;
        const int row0 = lp * 64;
        const int u = tid & 15, rr = tid >> 4;
        const int jc = u & 7, gp = u >> 3;
        const int ghid = wc * 8 + jc;
        const float* wA = lstm_Whh + (size_t)((2 * gp) * 512 + ghid) * 512;
        const float* wB = lstm_Whh + (size_t)((2 * gp + 1) * 512 + ghid) * 512;
        const float bA = lstm_bhh[(2 * gp) * 512 + ghid];
        const float bB = lstm_bhh[(2 * gp + 1) * 512 + ghid];
        float c4[4] = {0.f, 0.f, 0.f, 0.f};
        for (int t = 0; t < 32; ++t) {
            const int par = t & 1;
            for (int rc = 0; rc < 4; ++rc) {
                if (t > 0) {
                    const float* hsrc = lstm_hbuf + (size_t)par * 65536
                                      + (size_t)(row0 + rc * 16) * 512;
                    for (int s = tid; s < 8192; s += 256)
                        Msf[(s >> 9) * 520 + (s & 511)] =
                            ldc(hsrc + (size_t)(s >> 9) * 512 + (s & 511));
                }
                __syncthreads();
                const int grow = row0 + rc * 16 + rr;
                const float* gir = gi + ((size_t)t * 128 + grow) * 2048;
                float sA = bA + gir[(2 * gp) * 512 + ghid];
                float sB = bB + gir[(2 * gp + 1) * 512 + ghid];
                if (t > 0) {
                    const float* hr = Msf + rr * 520;
                    for (int k = 0; k < 512; k += 4) {
                        const float4 h4 = *(const float4*)(hr + k);
                        const float4 a4 = *(const float4*)(wA + k);
                        const float4 b4 = *(const float4*)(wB + k);
                        sA += h4.x*a4.x + h4.y*a4.y + h4.z*a4.z + h4.w*a4.w;
                        sB += h4.x*b4.x + h4.y*b4.y + h4.z*b4.z + h4.w*b4.w;
                    }
                }
                lgg[rr * 32 + jc * 4 + 2 * gp]     = sA;
                lgg[rr * 32 + jc * 4 + 2 * gp + 1] = sB;
                __syncthreads();
                if (tid < 128) {
                    const int r2 = tid >> 3, j2 = tid & 7;
                    const int grw = row0 + rc * 16 + r2;
                    const int gh2 = wc * 8 + j2;
                    const float si = lgg[r2 * 32 + j2 * 4 + 0];
                    const float sf = lgg[r2 * 32 + j2 * 4 + 1];
                    const float sg = lgg[r2 * 32 + j2 * 4 + 2];
                    const float so = lgg[r2 * 32 + j2 * 4 + 3];
                    const float c = sigf(sf) * c4[rc] + sigf(si) * tanhf(sg);
                    c4[rc] = c;
                    const float h = sigf(so) * tanhf(c);
                    stc(lstm_hbuf + (size_t)(1 - par) * 65536 + (size_t)grw * 512 + gh2, h);
                    lstm_out[((size_t)t * 128 + grw) * 512 + gh2] = h;
                }
                __syncthreads();
            }
            podbar(pbar, 64);
        }
        return;
    }

    // ============================= GNN ==================================
    const int pod = wg >> 6, w = wg & 63;
    int* pbar = bar + pod * 64;
    const int b0 = pod * 16, j0 = w * 8;
    const int wv = tid >> 6, lane = tid & 63;
    const int nI = lane & 15, quad = lane >> 4;
    unsigned* MbP = Mbuf + pod * 4096;   // [16][256] bf16-pair dwords
    unsigned* hxP = hxch + pod * 4096;
    float* VhW = Vh + (size_t)wg * 32768;  // [16][128][16]

    for (int s = tid; s < 512; s += 256) wkL[s] = attnW[512 + s];

    // ---- B fragments (hi/lo bf16 split), loaded ONCE into VGPRs ----
    const float* wrow;
    if (wv < 3) {
        const int c = (2 * wv + (nI >> 3)) * 512 + j0 + (nI & 7);
        wrow = (c < 1536) ? cWhh + (size_t)c * 512 : pWih + (size_t)(c - 1536) * 512;
    } else {
        wrow = ((nI >> 3) ? Wr1 : Wr0) + (size_t)(j0 + (nI & 7)) * 512;
    }
    s16x8 Bhi[16], Blo[16];
    #pragma unroll
    for (int kk = 0; kk < 16; ++kk) {
        const float* wp = wrow + kk * 32 + quad * 8;
        s16x8 hi, lo;
        #pragma unroll
        for (int e = 0; e < 8; ++e) {
            const float x = wp[e];
            const unsigned short hb = f2bf(x);
            hi[e] = (short)hb;
            lo[e] = (short)f2bf(x - bf2f(hb));
        }
        Bhi[kk] = hi; Blo[kk] = lo;
    }
    // combine-thread constants (6 gate biases for (b=tid>>3, jc=tid&7))
    const int cb_b = tid >> 3, cb_j = tid & 7;
    float gbias[6];
    if (tid < 128) {
        #pragma unroll
        for (int g = 0; g < 6; ++g) {
            const int c = g * 512 + j0 + cb_j;
            gbias[g] = (c < 1536) ? cbhh[c] : pbih[c - 1536];
        }
    }
    // zero M(0)
    if (w * 256 + tid < 4096) stcu(MbP + w * 256 + tid, 0u);
    podbar(pbar, 64);

    for (int i = 0; i < 128; ++i) {
        // ---------------- Phase 1: stage M, gate MFMA, combine h ---------
        for (int s = tid; s < 4096; s += 256) {
            const unsigned d = ldcu(MbP + s);
            *(unsigned*)(MbU + (s >> 8) * 520 + ((s & 255) << 1)) = d;
        }
        __syncthreads();
        if (wv < 3) {
            f32x4 acc = {0.f, 0.f, 0.f, 0.f};
            const unsigned short* ab = MbU + nI * 520 + quad * 8;
            #pragma unroll
            for (int kk = 0; kk < 16; ++kk) {
                const s16x8 a = *(const s16x8*)(ab + kk * 32);
                acc = __builtin_amdgcn_mfma_f32_16x16x32_bf16(a, Bhi[kk], acc, 0, 0, 0);
                acc = __builtin_amdgcn_mfma_f32_16x16x32_bf16(a, Blo[kk], acc, 0, 0, 0);
            }
            #pragma unroll
            for (int r = 0; r < 4; ++r)
                gg[(quad * 4 + r) * 48 + wv * 16 + nI] = acc[r];
        }
        __syncthreads();
        if (tid < 128) {
            const int b = cb_b, jc = cb_j, j = j0 + jc, bg = b0 + b;
            const float g0v = gg[b * 48 +  0 + jc] + gbias[0];
            const float g1v = gg[b * 48 +  8 + jc] + gbias[1];
            const float g2v = gg[b * 48 + 16 + jc] + gbias[2];
            const float g3v = gg[b * 48 + 24 + jc] + gbias[3];
            const float g4v = gg[b * 48 + 32 + jc] + gbias[4];
            const float g5v = gg[b * 48 + 40 + jc] + gbias[5];
            const float mv = bf2f(MbU[b * 520 + j]);
            const float* pc = preQc + ((size_t)bg * 128 + i) * 1536;
            const float* pp = preQp + ((size_t)bg * 128 + i) * 1536;
            const float qv = Hin[((size_t)bg * 128 + i) * 512 + j];
            const float rc = sigf(pc[j] + g0v);
            const float zc = sigf(pc[512 + j] + g1v);
            const float nc = tanhf(pc[1024 + j] + rc * g2v);
            const float oc = (1.f - zc) * nc + zc * mv;
            const float rp = sigf(g3v + pp[j]);
            const float zp = sigf(g4v + pp[512 + j]);
            const float np = tanhf(g5v + rp * pp[1024 + j]);
            const float op = (1.f - zp) * np + zp * qv;
            const float h = oc + op;
            htmp[b * 8 + jc] = h;
            Hout[((size_t)bg * 128 + i) * 512 + j] = h;
        }
        __syncthreads();
        if (tid < 64) {
            const int b = tid >> 2, p2 = tid & 3;
            const unsigned d = (unsigned)f2bf(htmp[b * 8 + p2 * 2])
                             | ((unsigned)f2bf(htmp[b * 8 + p2 * 2 + 1]) << 16);
            stcu(hxP + b * 256 + (j0 >> 1) + p2, d);
        }
        podbar(pbar, 64);

        // ---------------- Phase 2: stage h, V MFMA, hk, softmax, M' ------
        for (int s = tid; s < 4096; s += 256) {
            const unsigned d = ldcu(hxP + s);
            *(unsigned*)(MbU + (s >> 8) * 520 + ((s & 255) << 1)) = d;
        }
        __syncthreads();
        if (wv == 3) {
            f32x4 acc = {0.f, 0.f, 0.f, 0.f};
            const unsigned short* ab = MbU + nI * 520 + quad * 8;
            #pragma unroll
            for (int kk = 0; kk < 16; ++kk) {
                const s16x8 a = *(const s16x8*)(ab + kk * 32);
                acc = __builtin_amdgcn_mfma_f32_16x16x32_bf16(a, Bhi[kk], acc, 0, 0, 0);
                acc = __builtin_amdgcn_mfma_f32_16x16x32_bf16(a, Blo[kk], acc, 0, 0, 0);
            }
            #pragma unroll
            for (int r = 0; r < 4; ++r) {
                const int b = quad * 4 + r;
                vcur[b * 16 + nI] = acc[r];
                VhW[((size_t)b * 128 + i) * 16 + nI] = acc[r];
            }
        }
        {   // hk partials (lane-contiguous) + width-16 shuffle reduce
            const int bq = tid >> 4, u = tid & 15;
            const unsigned short* hr = MbU + bq * 520;
            float p = 0.f;
            #pragma unroll
            for (int kk = 0; kk < 32; ++kk) {
                const int k = u + kk * 16;
                p += bf2f(hr[k]) * wkL[k];
            }
            #pragma unroll
            for (int off = 8; off > 0; off >>= 1) p += __shfl_xor(p, off, 16);
            if (u == 0) eh[bq * 128 + i] = p;
        }
        __syncthreads();
        if (i < 127) {
            const int bq = tid >> 4, u = tid & 15;
            const float* arow = adj + ((size_t)(b0 + bq) * 128 + (i + 1)) * 128;
            float amx = -3.0e38f;
            for (int n = u; n <= i; n += 16)
                amx = fmaxf(amx, eh[bq * 128 + n] - (1.f - arow[n]) * 1e30f);
            #pragma unroll
            for (int off = 8; off > 0; off >>= 1)
                amx = fmaxf(amx, __shfl_xor(amx, off, 16));
            float es = 0.f;
            for (int n = u; n <= i; n += 16) {
                const float e = __expf(eh[bq * 128 + n] - (1.f - arow[n]) * 1e30f - amx);
                wsf[bq * 128 + n] = e;
                es += e;
            }
            #pragma unroll
            for (int off = 8; off > 0; off >>= 1) es += __shfl_xor(es, off, 16);
            if (u == 0) invZ[bq] = 1.f / es;
            __syncthreads();
            if (tid < 128) {
                const int b = cb_b, jc = cb_j;
                const float* srow = smk + ((size_t)(b0 + b) * 128 + (i + 1)) * 128;
                const float* vb = VhW + (size_t)b * 128 * 16;
                float acc2 = 0.f;
                for (int n = 0; n < i; ++n) {
                    const float wgt = wsf[b * 128 + n];
                    acc2 += wgt * ((srow[n] != 0.f) ? vb[n * 16 + jc] : vb[n * 16 + 8 + jc]);
                }
                acc2 += wsf[b * 128 + i] *
                        ((srow[i] != 0.f) ? vcur[b * 16 + jc] : vcur[b * 16 + 8 + jc]);
                mpr[b * 8 + jc] = acc2 * invZ[b];
            }
            __syncthreads();
            if (tid < 64) {
                const int b = tid >> 2, p2 = tid & 3;
                const unsigned d = (unsigned)f2bf(mpr[b * 8 + p2 * 2])
                                 | ((unsigned)f2bf(mpr[b * 8 + p2 * 2 + 1]) << 16);
                stcu(MbP + b * 256 + (j0 >> 1) + p2, d);
            }
        }
        podbar(pbar, 64);
    }
}

// ---------------------------------------------------------------------------
__global__ __launch_bounds__(256) void out_gemm(
    const float* __restrict__ x2, const float* __restrict__ W,
    const float* __restrict__ bias, float* __restrict__ out)
{
    __shared__ float xs[16 * 516];
    const int tid = threadIdx.x;
    const int r0 = blockIdx.x * 16;
    for (int idx = tid; idx < 16 * 512; idx += 256) {
        const int rr = idx >> 9, kk = idx & 511;
        xs[rr * 516 + kk] = x2[(size_t)(r0 + rr) * 512 + kk];
    }
    __syncthreads();
    if (tid < 128) {
        const int r = tid >> 3, c = tid & 7;
        if (c < 7) {
            float acc = bias[c];
            const float* wr = W + c * 512;
            const float* xr = xs + r * 516;
            for (int k = 0; k < 512; ++k) acc += xr[k] * wr[k];
            out[(size_t)(r0 + r) * 7 + c] = acc;
        }
    }
}

// ---------------------------------------------------------------------------
extern "C" void kernel_launch(void* const* d_in, const int* in_sizes, int n_in,
                              void* d_out, int out_size, void* d_ws, size_t ws_size,
                              hipStream_t stream) {
    (void)in_sizes; (void)n_in; (void)out_size; (void)ws_size;
    const float* feat     = (const float*)d_in[0];
    const float* adj      = (const float*)d_in[1];
    const float* smask    = (const float*)d_in[2];
    const float* lstm_Wih = (const float*)d_in[5];
    const float* lstm_Whh = (const float*)d_in[6];
    const float* lstm_bih = (const float*)d_in[7];
    const float* lstm_bhh = (const float*)d_in[8];
    const float* fc1_W    = (const float*)d_in[9];
    const float* fc1_b    = (const float*)d_in[10];
    const float* attn_W   = (const float*)d_in[11];
    const float* Wr0      = (const float*)d_in[13];
    const float* Wr1      = (const float*)d_in[14];
    const float* gruC_Wih = (const float*)d_in[15];
    const float* gruC_Whh = (const float*)d_in[16];
    const float* gruC_bih = (const float*)d_in[17];
    const float* gruC_bhh = (const float*)d_in[18];
    const float* gruP_Wih = (const float*)d_in[19];
    const float* gruP_Whh = (const float*)d_in[20];
    const float* gruP_bih = (const float*)d_in[21];
    const float* gruP_bhh = (const float*)d_in[22];
    const float* mlp0_W   = (const float*)d_in[23];
    const float* mlp0_b   = (const float*)d_in[24];
    const float* mlp1_W   = (const float*)d_in[25];
    const float* mlp1_b   = (const float*)d_in[26];
    const float* out_W    = (const float*)d_in[27];
    const float* out_b    = (const float*)d_in[28];

    float* ws       = (float*)d_ws;
    float* lstm_gi  = ws;                        // 8,388,608
    float* lstm_out = lstm_gi + 8388608;         // 2,097,152
    float* H0       = lstm_out + 2097152;        // 2,097,152
    float* H1       = H0 + 2097152;              // 2,097,152
    float* H2       = H1 + 2097152;              // 2,097,152
    float* preQc    = H2 + 2097152;              // 6,291,456
    float* preQp    = preQc + 6291456;           // 6,291,456
    float* x1       = preQp + 6291456;           // 2,097,152
    float* x2       = x1 + 2097152;              // 2,097,152
    unsigned* Mbuf  = (unsigned*)(x2 + 2097152); // 8,192 dwords
    unsigned* hxch  = Mbuf + 8192;               // 8,192 dwords
    float* Vh       = (float*)(hxch + 8192);     // 4,194,304
    float* lstm_hb  = Vh + 4194304;              // 131,072
    int*   bar      = (int*)(lstm_hb + 131072);  // 1,024 ints

    const dim3 blk(256);
    init_bar<<<1, 1024, 0, stream>>>(bar);

    // parallel-phase GEMMs
    gemm_nt<<<dim3(64, 8), blk, 0, stream>>>(feat, fc1_W, fc1_b, H0, 4096, 512, 1024, 1);
    gemm_nt<<<dim3(64, 32), blk, 0, stream>>>(feat, lstm_Wih, lstm_bih, lstm_gi, 4096, 2048, 1024, 0);
    gemm_nt<<<dim3(64, 24), blk, 0, stream>>>(H0, gruC_Wih, gruC_bih, preQc, 4096, 1536, 512, 0);
    gemm_nt<<<dim3(64, 24), blk, 0, stream>>>(H0, gruP_Whh, gruP_bhh, preQp, 4096, 1536, 512, 0);

    // layer 0 scan (+ LSTM on WGs 128..255)
    scan_layer<<<256, blk, 0, stream>>>(
        H0, H1, adj, smask, preQc, preQp,
        gruC_Whh, gruP_Wih, gruC_bhh, gruP_bih, attn_W,
        Wr0, Wr1, Mbuf, hxch, Vh, bar, 1,
        lstm_gi, lstm_Whh, lstm_bhh, lstm_hb, lstm_out);

    // layer-1 preQ
    gemm_nt<<<dim3(64, 24), blk, 0, stream>>>(H1, gruC_Wih + (size_t)1536 * 512,
                                              gruC_bih + 1536, preQc, 4096, 1536, 512, 0);
    gemm_nt<<<dim3(64, 24), blk, 0, stream>>>(H1, gruP_Whh + (size_t)1536 * 512,
                                              gruP_bhh + 1536, preQp, 4096, 1536, 512, 0);

    // layer 1 scan (GNN only, 128 WGs)
    scan_layer<<<128, blk, 0, stream>>>(
        H1, H2, adj, smask, preQc, preQp,
        gruC_Whh + (size_t)1536 * 512, gruP_Wih + (size_t)1536 * 512,
        gruC_bhh + 1536, gruP_bih + 1536, attn_W + 1024,
        Wr0 + (size_t)512 * 512, Wr1 + (size_t)512 * 512,
        Mbuf, hxch, Vh, bar, 0,
        lstm_gi, lstm_Whh, lstm_bhh, lstm_hb, lstm_out);

    // head
    gemm_cat<<<dim3(64, 8), blk, 0, stream>>>(H0, H1, H2, feat, lstm_out, mlp0_W, mlp0_b, x1);
    gemm_nt<<<dim3(64, 8), blk, 0, stream>>>(x1, mlp1_W, mlp1_b, x2, 4096, 512, 512, 1);
    out_gemm<<<256, blk, 0, stream>>>(x2, out_W, out_b, (float*)d_out);
}